// Round 9
// baseline (256.462 us; speedup 1.0000x reference)
//
#include <hip/hip_runtime.h>
#include <hip/hip_bf16.h>

// LinearAttention: B=8, N=4096, D=256, HW=N.
//  q_bf  = bf16(query); kv_bf = bf16(key_value^T per batch)
//  Qb = elu(q_bf@Wq^T+bq)+1 ; Kb likewise ; Vb = kv_bf@Wv^T+bv
//  Kt = Kb^T, Vt = Vb^T (global transpose)
//  KV[b][c][d] = sum_m Kb[m,c]*Vb[m,d]   (plain GEMM on Kt,Vt; split-K + reduce -> bf16)
//  W2T[b][e][c] = sum_d Wo[e,d]*KV[b][c][d]   (small per-batch GEMM)
//  den[b,n] = rowsum(Qb)*rowsum(Kb)
//  d_out[n,e] = (sum_c Qb[n,c]*W2T[e,c])/(den+1e-6) + bo[e]   (fused: (num/den)@Wo^T == (num@Wo^T)/den)

typedef __attribute__((ext_vector_type(8))) __bf16 bf16x8;
typedef __attribute__((ext_vector_type(4))) float f32x4;
typedef __attribute__((ext_vector_type(4))) unsigned short u16x4;
typedef __attribute__((ext_vector_type(8))) unsigned short u16x8;

#define DEVI __device__ __forceinline__

static constexpr int BATCH = 8;
static constexpr int NTOK  = 4096;
static constexpr int DDIM  = 256;

DEVI float bf2f(unsigned short u) {
  union { float f; unsigned int i; } x; x.i = ((unsigned int)u) << 16; return x.f;
}
DEVI unsigned short f2bf(float f) {
  union { float f; unsigned int i; } x; x.f = f;
  unsigned int r = x.i + 0x7fffu + ((x.i >> 16) & 1u);
  return (unsigned short)(r >> 16);
}

// ---------- conversion kernels ----------
__global__ __launch_bounds__(256) void conv_q_kernel(const float* __restrict__ src,
                                                     unsigned short* __restrict__ dst) {
  size_t base = ((size_t)blockIdx.x * 256 + threadIdx.x) * 16;
#pragma unroll
  for (int j = 0; j < 4; ++j) {
    float4 v = *reinterpret_cast<const float4*>(src + base + j * 4);
    u16x4 o = { f2bf(v.x), f2bf(v.y), f2bf(v.z), f2bf(v.w) };
    *reinterpret_cast<u16x4*>(dst + base + j * 4) = o;
  }
}

__global__ __launch_bounds__(256) void conv_w_kernel(const float* __restrict__ w0, const float* __restrict__ w1,
                                                     const float* __restrict__ w2, const float* __restrict__ w3,
                                                     unsigned short* __restrict__ o0, unsigned short* __restrict__ o1,
                                                     unsigned short* __restrict__ o2, unsigned short* __restrict__ o3) {
  size_t i = ((size_t)blockIdx.x * 256 + threadIdx.x) * 4;
  float4 a = *reinterpret_cast<const float4*>(w0 + i);
  float4 b = *reinterpret_cast<const float4*>(w1 + i);
  float4 c = *reinterpret_cast<const float4*>(w2 + i);
  float4 d = *reinterpret_cast<const float4*>(w3 + i);
  u16x4 oa = { f2bf(a.x), f2bf(a.y), f2bf(a.z), f2bf(a.w) };
  u16x4 ob = { f2bf(b.x), f2bf(b.y), f2bf(b.z), f2bf(b.w) };
  u16x4 oc = { f2bf(c.x), f2bf(c.y), f2bf(c.z), f2bf(c.w) };
  u16x4 od = { f2bf(d.x), f2bf(d.y), f2bf(d.z), f2bf(d.w) };
  *reinterpret_cast<u16x4*>(o0 + i) = oa;
  *reinterpret_cast<u16x4*>(o1 + i) = ob;
  *reinterpret_cast<u16x4*>(o2 + i) = oc;
  *reinterpret_cast<u16x4*>(o3 + i) = od;
}

// key_value [B][D][M] fp32 -> kv_bf [B][M][D] bf16
__global__ __launch_bounds__(256) void kv_transpose(const float* __restrict__ src,
                                                    unsigned short* __restrict__ dst) {
  __shared__ float t[32][33];
  int b = blockIdx.z;
  int m0 = blockIdx.x * 32, d0 = blockIdx.y * 32;
  int tx = threadIdx.x, ty = threadIdx.y; // 32 x 8
  const float* s = src + ((size_t)b * DDIM + d0) * NTOK + m0;
#pragma unroll
  for (int i = 0; i < 4; ++i) t[ty + i * 8][tx] = s[(size_t)(ty + i * 8) * NTOK + tx];
  __syncthreads();
  unsigned short* d = dst + ((size_t)b * NTOK + m0) * DDIM + d0;
#pragma unroll
  for (int i = 0; i < 4; ++i) d[(size_t)(ty + i * 8) * DDIM + tx] = f2bf(t[tx][ty + i * 8]);
}

// bf16 [B][4096][256] -> bf16 [B][256][4096]  (64x64 tiles)
__global__ __launch_bounds__(256) void t64_kernel(const unsigned short* __restrict__ src,
                                                  unsigned short* __restrict__ dst) {
  constexpr int LDT = 68;
  __shared__ unsigned short Ts[64 * LDT];
  const int tid = threadIdx.x;
  const int b = blockIdx.z;
  const int m0 = blockIdx.x * 64;
  const int c0 = blockIdx.y * 64;
  {
    const int cg = tid & 15;
    const int rb = tid >> 4;
#pragma unroll
    for (int it = 0; it < 4; ++it) {
      int r = rb + it * 16;
      u16x4 v = *reinterpret_cast<const u16x4*>(src + ((size_t)b * NTOK + m0 + r) * 256 + c0 + cg * 4);
      *reinterpret_cast<u16x4*>(&Ts[r * LDT + cg * 4]) = v;
    }
  }
  __syncthreads();
  {
    const int c = tid >> 2;
    const int mg = tid & 3;
    u16x8 o0, o1;
#pragma unroll
    for (int j = 0; j < 8; ++j) o0[j] = Ts[(mg * 16 + j) * LDT + c];
#pragma unroll
    for (int j = 0; j < 8; ++j) o1[j] = Ts[(mg * 16 + 8 + j) * LDT + c];
    unsigned short* d = dst + ((size_t)b * DDIM + c0 + c) * NTOK + m0 + mg * 16;
    *reinterpret_cast<u16x8*>(d) = o0;
    *reinterpret_cast<u16x8*>(d + 8) = o1;
  }
}

// ---------- projection GEMM: C = act(A @ W^T + bias) ----------
template <int ACT>
__global__ __launch_bounds__(256) void gemm_proj(const unsigned short* __restrict__ A,
                                                 const unsigned short* __restrict__ W,
                                                 const float* __restrict__ bias,
                                                 unsigned short* __restrict__ outp) {
  constexpr int LDT = 72;
  __shared__ unsigned short As[128 * LDT];
  __shared__ unsigned short Ws[128 * LDT];

  const int tid = threadIdx.x;
  const int m0 = blockIdx.x * 128;
  const int c0 = blockIdx.y * 128;
  const int w = tid >> 6, l = tid & 63;
  const int wr = (w >> 1) * 64, wc = (w & 1) * 64;
  const int lr = l & 15, lk = (l >> 4) * 8;

  f32x4 acc[4][4] = {};

  for (int k0 = 0; k0 < 256; k0 += 64) {
#pragma unroll
    for (int it = 0; it < 4; ++it) {
      int idx = tid + it * 256;
      int r = idx >> 3;
      int c = (idx & 7) * 8;
      *reinterpret_cast<u16x8*>(&As[r * LDT + c]) =
          *reinterpret_cast<const u16x8*>(A + (size_t)(m0 + r) * 256 + k0 + c);
      *reinterpret_cast<u16x8*>(&Ws[r * LDT + c]) =
          *reinterpret_cast<const u16x8*>(W + (size_t)(c0 + r) * 256 + k0 + c);
    }
    __syncthreads();
#pragma unroll
    for (int kk = 0; kk < 2; ++kk) {
      bf16x8 a[4], b[4];
#pragma unroll
      for (int m = 0; m < 4; ++m)
        a[m] = *reinterpret_cast<const bf16x8*>(&As[(wr + m * 16 + lr) * LDT + kk * 32 + lk]);
#pragma unroll
      for (int n = 0; n < 4; ++n)
        b[n] = *reinterpret_cast<const bf16x8*>(&Ws[(wc + n * 16 + lr) * LDT + kk * 32 + lk]);
#pragma unroll
      for (int m = 0; m < 4; ++m)
#pragma unroll
        for (int n = 0; n < 4; ++n)
          acc[m][n] = __builtin_amdgcn_mfma_f32_16x16x32_bf16(a[m], b[n], acc[m][n], 0, 0, 0);
    }
    __syncthreads();
  }

#pragma unroll
  for (int n = 0; n < 4; ++n) {
    const int col = c0 + wc + n * 16 + lr;
    const float bv = bias[col];
#pragma unroll
    for (int m = 0; m < 4; ++m) {
#pragma unroll
      for (int j = 0; j < 4; ++j) {
        int row = m0 + wr + m * 16 + (l >> 4) * 4 + j;
        float x = acc[m][n][j] + bv;
        if (ACT) x = (x > 0.0f) ? (x + 1.0f) : __expf(x);
        outp[(size_t)row * 256 + col] = f2bf(x);
      }
    }
  }
}

// ---------- den[b,n] = rowsum(Qb)*rowsum(Kb) ----------
__global__ __launch_bounds__(256) void den_kernel(const unsigned short* __restrict__ Qb,
                                                  const unsigned short* __restrict__ Kb,
                                                  float* __restrict__ den) {
  int row = blockIdx.x * 4 + (threadIdx.x >> 6);
  int l = threadIdx.x & 63;
  u16x4 q = *reinterpret_cast<const u16x4*>(Qb + (size_t)row * 256 + l * 4);
  u16x4 k = *reinterpret_cast<const u16x4*>(Kb + (size_t)row * 256 + l * 4);
  float qs = bf2f(q[0]) + bf2f(q[1]) + bf2f(q[2]) + bf2f(q[3]);
  float ks = bf2f(k[0]) + bf2f(k[1]) + bf2f(k[2]) + bf2f(k[3]);
#pragma unroll
  for (int s = 32; s > 0; s >>= 1) {
    qs += __shfl_xor(qs, s);
    ks += __shfl_xor(ks, s);
  }
  if (l == 0) den[row] = qs * ks;
}

// ---------- KV partials: A=Kt rows(c), B=Vt rows(d), k=m ----------
// partial[s][b][c][d] = sum_{m in split s} Kt[b][c][m] * Vt[b][d][m]
__global__ __launch_bounds__(256) void kv_gemm(const unsigned short* __restrict__ Kt,
                                               const unsigned short* __restrict__ Vt,
                                               float* __restrict__ partial) {
  constexpr int LDT = 72;
  __shared__ unsigned short As[128 * LDT]; // Kt rows (c)
  __shared__ unsigned short Bs[128 * LDT]; // Vt rows (d)
  const int tid = threadIdx.x;
  const int b = blockIdx.z;
  const int s = blockIdx.y;
  const int ct0 = (blockIdx.x >> 1) * 128;
  const int dt0 = (blockIdx.x & 1) * 128;
  const int ms = s * 512;

  const int w = tid >> 6, l = tid & 63;
  const int wr = (w >> 1) * 64, wc = (w & 1) * 64;
  const int lr = l & 15, lk = (l >> 4) * 8;

  const size_t kbase = ((size_t)b * DDIM + ct0) * NTOK;
  const size_t vbase = ((size_t)b * DDIM + dt0) * NTOK;

  f32x4 acc[4][4] = {};

  for (int mc = 0; mc < 512; mc += 64) {
#pragma unroll
    for (int it = 0; it < 4; ++it) {
      int idx = tid + it * 256;
      int r = idx >> 3;
      int kg = (idx & 7) * 8;
      *reinterpret_cast<u16x8*>(&As[r * LDT + kg]) =
          *reinterpret_cast<const u16x8*>(Kt + kbase + (size_t)r * NTOK + ms + mc + kg);
      *reinterpret_cast<u16x8*>(&Bs[r * LDT + kg]) =
          *reinterpret_cast<const u16x8*>(Vt + vbase + (size_t)r * NTOK + ms + mc + kg);
    }
    __syncthreads();
#pragma unroll
    for (int kk = 0; kk < 2; ++kk) {
      bf16x8 a[4], bb[4];
#pragma unroll
      for (int m = 0; m < 4; ++m)
        a[m] = *reinterpret_cast<const bf16x8*>(&As[(wr + m * 16 + lr) * LDT + kk * 32 + lk]);
#pragma unroll
      for (int n = 0; n < 4; ++n)
        bb[n] = *reinterpret_cast<const bf16x8*>(&Bs[(wc + n * 16 + lr) * LDT + kk * 32 + lk]);
#pragma unroll
      for (int m = 0; m < 4; ++m)
#pragma unroll
        for (int n = 0; n < 4; ++n)
          acc[m][n] = __builtin_amdgcn_mfma_f32_16x16x32_bf16(a[m], bb[n], acc[m][n], 0, 0, 0);
    }
    __syncthreads();
  }

  float* p = partial + (size_t)(s * BATCH + b) * 65536;
#pragma unroll
  for (int n = 0; n < 4; ++n) {
    int d = dt0 + wc + n * 16 + lr;                 // B-side row
#pragma unroll
    for (int m = 0; m < 4; ++m) {
#pragma unroll
      for (int j = 0; j < 4; ++j) {
        int c = ct0 + wr + m * 16 + (l >> 4) * 4 + j; // A-side row
        p[(size_t)c * 256 + d] = acc[m][n][j];
      }
    }
  }
}

// ---------- KVb[b][c][d] = bf16( sum_s partial[s][b][c][d] ) ----------
__global__ __launch_bounds__(256) void kv_reduce(const float* __restrict__ partial,
                                                 unsigned short* __restrict__ KVb) {
  size_t i = ((size_t)blockIdx.x * 256 + threadIdx.x) * 4;
  float4 acc = *reinterpret_cast<const float4*>(partial + i);
#pragma unroll
  for (int s = 1; s < 8; ++s) {
    float4 v = *reinterpret_cast<const float4*>(partial + (size_t)s * 524288 + i);
    acc.x += v.x; acc.y += v.y; acc.z += v.z; acc.w += v.w;
  }
  u16x4 o = { f2bf(acc.x), f2bf(acc.y), f2bf(acc.z), f2bf(acc.w) };
  *reinterpret_cast<u16x4*>(KVb + i) = o;
}

// ---------- W2T[b][e][c] = sum_d Wo[e,d] * KV[b][c][d]  (small per-batch GEMM) ----------
__global__ __launch_bounds__(256) void w2_gemm(const unsigned short* __restrict__ wob,
                                               const unsigned short* __restrict__ KVb,
                                               unsigned short* __restrict__ W2T) {
  constexpr int LDT = 72;
  __shared__ unsigned short As[128 * LDT]; // Wo rows (e)
  __shared__ unsigned short Bs[128 * LDT]; // KV rows (c)
  const int tid = threadIdx.x;
  const int b = blockIdx.z;
  const int e0 = blockIdx.x * 128;
  const int c0 = blockIdx.y * 128;
  const unsigned short* Bsrc = KVb + (size_t)b * 65536;

  const int w = tid >> 6, l = tid & 63;
  const int wr = (w >> 1) * 64, wc = (w & 1) * 64;
  const int lr = l & 15, lk = (l >> 4) * 8;

  f32x4 acc[4][4] = {};

  for (int k0 = 0; k0 < 256; k0 += 64) {
#pragma unroll
    for (int it = 0; it < 4; ++it) {
      int idx = tid + it * 256;
      int r = idx >> 3;
      int c = (idx & 7) * 8;
      *reinterpret_cast<u16x8*>(&As[r * LDT + c]) =
          *reinterpret_cast<const u16x8*>(wob + (size_t)(e0 + r) * 256 + k0 + c);
      *reinterpret_cast<u16x8*>(&Bs[r * LDT + c]) =
          *reinterpret_cast<const u16x8*>(Bsrc + (size_t)(c0 + r) * 256 + k0 + c);
    }
    __syncthreads();
#pragma unroll
    for (int kk = 0; kk < 2; ++kk) {
      bf16x8 a[4], bb[4];
#pragma unroll
      for (int m = 0; m < 4; ++m)
        a[m] = *reinterpret_cast<const bf16x8*>(&As[(wr + m * 16 + lr) * LDT + kk * 32 + lk]);
#pragma unroll
      for (int n = 0; n < 4; ++n)
        bb[n] = *reinterpret_cast<const bf16x8*>(&Bs[(wc + n * 16 + lr) * LDT + kk * 32 + lk]);
#pragma unroll
      for (int m = 0; m < 4; ++m)
#pragma unroll
        for (int n = 0; n < 4; ++n)
          acc[m][n] = __builtin_amdgcn_mfma_f32_16x16x32_bf16(a[m], bb[n], acc[m][n], 0, 0, 0);
    }
    __syncthreads();
  }

  unsigned short* out = W2T + (size_t)b * 65536;
#pragma unroll
  for (int n = 0; n < 4; ++n) {
    int c = c0 + wc + n * 16 + lr;
#pragma unroll
    for (int m = 0; m < 4; ++m) {
#pragma unroll
      for (int j = 0; j < 4; ++j) {
        int e = e0 + wr + m * 16 + (l >> 4) * 4 + j;
        out[(size_t)e * 256 + c] = f2bf(acc[m][n][j]);
      }
    }
  }
}

// ---------- d_out[b,n,e] = (Qb @ W2T^T)/(den+1e-6) + bo ----------
__global__ __launch_bounds__(256) void gemm_final(const unsigned short* __restrict__ Qb,
                                                  const unsigned short* __restrict__ W2T,
                                                  const float* __restrict__ den,
                                                  const float* __restrict__ bo,
                                                  float* __restrict__ outp) {
  constexpr int LDT = 72;
  __shared__ unsigned short As[128 * LDT];
  __shared__ unsigned short Bs[128 * LDT];
  const int tid = threadIdx.x;
  const int b = blockIdx.z;
  const int m0 = blockIdx.x * 128;
  const int e0 = blockIdx.y * 128;
  const size_t abase = (size_t)b * NTOK;
  const unsigned short* Bsrc = W2T + (size_t)b * 65536;

  const int w = tid >> 6, l = tid & 63;
  const int wr = (w >> 1) * 64, wc = (w & 1) * 64;
  const int lr = l & 15, lk = (l >> 4) * 8;

  f32x4 acc[4][4] = {};

  for (int k0 = 0; k0 < 256; k0 += 64) {
#pragma unroll
    for (int it = 0; it < 4; ++it) {
      int idx = tid + it * 256;
      int r = idx >> 3, c = (idx & 7) * 8;
      *reinterpret_cast<u16x8*>(&As[r * LDT + c]) =
          *reinterpret_cast<const u16x8*>(Qb + (abase + m0 + r) * 256 + k0 + c);
      *reinterpret_cast<u16x8*>(&Bs[r * LDT + c]) =
          *reinterpret_cast<const u16x8*>(Bsrc + (size_t)(e0 + r) * 256 + k0 + c);
    }
    __syncthreads();
#pragma unroll
    for (int kk = 0; kk < 2; ++kk) {
      bf16x8 a[4], bb[4];
#pragma unroll
      for (int m = 0; m < 4; ++m)
        a[m] = *reinterpret_cast<const bf16x8*>(&As[(wr + m * 16 + lr) * LDT + kk * 32 + lk]);
#pragma unroll
      for (int n = 0; n < 4; ++n)
        bb[n] = *reinterpret_cast<const bf16x8*>(&Bs[(wc + n * 16 + lr) * LDT + kk * 32 + lk]);
#pragma unroll
      for (int m = 0; m < 4; ++m)
#pragma unroll
        for (int n = 0; n < 4; ++n)
          acc[m][n] = __builtin_amdgcn_mfma_f32_16x16x32_bf16(a[m], bb[n], acc[m][n], 0, 0, 0);
    }
    __syncthreads();
  }

#pragma unroll
  for (int n = 0; n < 4; ++n) {
    int col = e0 + wc + n * 16 + lr;
    const float bv = bo[col];
#pragma unroll
    for (int m = 0; m < 4; ++m) {
#pragma unroll
      for (int j = 0; j < 4; ++j) {
        int row = m0 + wr + m * 16 + (l >> 4) * 4 + j;
        float dv = den[abase + row] + 1e-6f;
        outp[(abase + row) * 256 + col] = acc[m][n][j] / dv + bv;
      }
    }
  }
}

extern "C" void kernel_launch(void* const* d_in, const int* in_sizes, int n_in,
                              void* d_out, int out_size, void* d_ws, size_t ws_size,
                              hipStream_t stream) {
  const float* query     = (const float*)d_in[0];
  const float* key_value = (const float*)d_in[1];
  const float* Wq = (const float*)d_in[2];
  const float* bq = (const float*)d_in[3];
  const float* Wk = (const float*)d_in[4];
  const float* bk = (const float*)d_in[5];
  const float* Wv = (const float*)d_in[6];
  const float* bv = (const float*)d_in[7];
  const float* Wo = (const float*)d_in[8];
  const float* bo = (const float*)d_in[9];

  char* ws = (char*)d_ws;
  const size_t MB = 1ull << 20;
  // lifetimes: q_bf dead after projQ -> Kt; kv_bf dead after projV -> Vt;
  // Vb dead after t64(V) -> partial; Kt/Vt dead after kv_gemm.
  unsigned short* q_bf  = (unsigned short*)(ws + 0 * MB);   // 16MB; later Kt
  unsigned short* kv_bf = (unsigned short*)(ws + 16 * MB);  // 16MB; later Vt
  unsigned short* Qb    = (unsigned short*)(ws + 32 * MB);  // 16MB
  unsigned short* Kb    = (unsigned short*)(ws + 48 * MB);  // 16MB
  unsigned short* Vb    = (unsigned short*)(ws + 64 * MB);  // 16MB; later partial
  unsigned short* KVb   = (unsigned short*)(ws + 80 * MB);  // 1MB  bf16 KV[c][d]
  unsigned short* W2T   = (unsigned short*)(ws + 81 * MB);  // 1MB  bf16 W2T[e][c]
  float* den            = (float*)(ws + 82 * MB);           // 128KB
  unsigned short* wqb   = (unsigned short*)(ws + 82 * MB + 128 * 1024);
  unsigned short* wkb   = (unsigned short*)(ws + 82 * MB + 256 * 1024);
  unsigned short* wvb   = (unsigned short*)(ws + 82 * MB + 384 * 1024);
  unsigned short* wob   = (unsigned short*)(ws + 82 * MB + 512 * 1024);
  unsigned short* Kt    = q_bf;
  unsigned short* Vt    = kv_bf;
  float* partial        = (float*)(ws + 64 * MB);           // 16MB (8 splits x 2MB)

  conv_q_kernel<<<2048, 256, 0, stream>>>(query, q_bf);
  conv_w_kernel<<<64, 256, 0, stream>>>(Wq, Wk, Wv, Wo, wqb, wkb, wvb, wob);
  kv_transpose<<<dim3(128, 8, 8), dim3(32, 8), 0, stream>>>(key_value, kv_bf);

  gemm_proj<1><<<dim3(256, 2), 256, 0, stream>>>(q_bf, wqb, bq, Qb);   // q_bf dead
  gemm_proj<1><<<dim3(256, 2), 256, 0, stream>>>(kv_bf, wkb, bk, Kb);
  gemm_proj<0><<<dim3(256, 2), 256, 0, stream>>>(kv_bf, wvb, bv, Vb);  // kv_bf dead

  t64_kernel<<<dim3(64, 4, 8), 256, 0, stream>>>(Kb, Kt);
  t64_kernel<<<dim3(64, 4, 8), 256, 0, stream>>>(Vb, Vt);              // Vb dead

  den_kernel<<<8192, 256, 0, stream>>>(Qb, Kb, den);                   // Kb dead
  kv_gemm<<<dim3(4, 8, 8), 256, 0, stream>>>(Kt, Vt, partial);         // Kt,Vt dead after
  kv_reduce<<<512, 256, 0, stream>>>(partial, KVb);                    // partial dead
  w2_gemm<<<dim3(2, 2, 8), 256, 0, stream>>>(wob, KVb, W2T);

  gemm_final<<<dim3(32, 2, 8), 256, 0, stream>>>(Qb, W2T, den, bo, (float*)d_out);
}

// Round 12
// 225.479 us; speedup vs baseline: 1.1374x; 1.1374x over previous
//
#include <hip/hip_runtime.h>
#include <hip/hip_bf16.h>

// LinearAttention: B=8, N=4096, D=256, HW=N.
//  kv_bf = bf16(key_value^T per batch)                         (kv_transpose)
//  Qb = elu(query@Wq^T+bq)+1 (fp32 A staged directly), qsum[row] += rowsum   (projQ)
//  Kt = (elu(kv_bf@Wk^T+bk)+1)^T, Vt = (kv_bf@Wv^T+bv)^T, ksum (projKV, fused A, transposed epilogue)
//  KV[b][c][d] = sum_m K[m,c]*V[m,d]            (kv_gemm split-K + kv_reduce -> bf16)
//  W2T[b][e][c] = sum_d Wo[e,d]*KV[b][c][d]     (w2_gemm)
//  d_out[n,e] = (Qb @ W2T^T)/(qsum*ksum+1e-6) + bo             (gemm_final)

typedef __attribute__((ext_vector_type(8))) __bf16 bf16x8;
typedef __attribute__((ext_vector_type(4))) float f32x4;
typedef __attribute__((ext_vector_type(4))) unsigned short u16x4;
typedef __attribute__((ext_vector_type(8))) unsigned short u16x8;

#define DEVI __device__ __forceinline__

static constexpr int BATCH = 8;
static constexpr int NTOK  = 4096;
static constexpr int DDIM  = 256;

DEVI float bf2f(unsigned short u) {
  union { float f; unsigned int i; } x; x.i = ((unsigned int)u) << 16; return x.f;
}
DEVI unsigned short f2bf(float f) {
  union { float f; unsigned int i; } x; x.f = f;
  unsigned int r = x.i + 0x7fffu + ((x.i >> 16) & 1u);
  return (unsigned short)(r >> 16);
}

// ---------- weights fp32 -> bf16 ----------
__global__ __launch_bounds__(256) void conv_w_kernel(const float* __restrict__ w0, const float* __restrict__ w1,
                                                     const float* __restrict__ w2, const float* __restrict__ w3,
                                                     unsigned short* __restrict__ o0, unsigned short* __restrict__ o1,
                                                     unsigned short* __restrict__ o2, unsigned short* __restrict__ o3) {
  size_t i = ((size_t)blockIdx.x * 256 + threadIdx.x) * 4;
  float4 a = *reinterpret_cast<const float4*>(w0 + i);
  float4 b = *reinterpret_cast<const float4*>(w1 + i);
  float4 c = *reinterpret_cast<const float4*>(w2 + i);
  float4 d = *reinterpret_cast<const float4*>(w3 + i);
  u16x4 oa = { f2bf(a.x), f2bf(a.y), f2bf(a.z), f2bf(a.w) };
  u16x4 ob = { f2bf(b.x), f2bf(b.y), f2bf(b.z), f2bf(b.w) };
  u16x4 oc = { f2bf(c.x), f2bf(c.y), f2bf(c.z), f2bf(c.w) };
  u16x4 od = { f2bf(d.x), f2bf(d.y), f2bf(d.z), f2bf(d.w) };
  *reinterpret_cast<u16x4*>(o0 + i) = oa;
  *reinterpret_cast<u16x4*>(o1 + i) = ob;
  *reinterpret_cast<u16x4*>(o2 + i) = oc;
  *reinterpret_cast<u16x4*>(o3 + i) = od;
}

// key_value [B][D][M] fp32 -> kv_bf [B][M][D] bf16
__global__ __launch_bounds__(256) void kv_transpose(const float* __restrict__ src,
                                                    unsigned short* __restrict__ dst) {
  __shared__ float t[32][33];
  int b = blockIdx.z;
  int m0 = blockIdx.x * 32, d0 = blockIdx.y * 32;
  int tx = threadIdx.x, ty = threadIdx.y; // 32 x 8
  const float* s = src + ((size_t)b * DDIM + d0) * NTOK + m0;
#pragma unroll
  for (int i = 0; i < 4; ++i) t[ty + i * 8][tx] = s[(size_t)(ty + i * 8) * NTOK + tx];
  __syncthreads();
  unsigned short* d = dst + ((size_t)b * NTOK + m0) * DDIM + d0;
#pragma unroll
  for (int i = 0; i < 4; ++i) d[(size_t)(ty + i * 8) * DDIM + tx] = f2bf(t[tx][ty + i * 8]);
}

// ---------- projQ: Qb = elu(query@Wq^T+bq)+1, qsum += rowsum ----------
__global__ __launch_bounds__(256) void gemm_projq(const float* __restrict__ A,
                                                  const unsigned short* __restrict__ W,
                                                  const float* __restrict__ bias,
                                                  unsigned short* __restrict__ Qb,
                                                  float* __restrict__ qsum) {
  constexpr int LDT = 72;
  __shared__ unsigned short As[128 * LDT];
  __shared__ unsigned short Ws[128 * LDT];

  const int tid = threadIdx.x;
  const int m0 = blockIdx.x * 128;
  const int c0 = blockIdx.y * 128;
  const int w = tid >> 6, l = tid & 63;
  const int wr = (w >> 1) * 64, wc = (w & 1) * 64;
  const int lr = l & 15, lk = (l >> 4) * 8;

  f32x4 acc[4][4] = {};

  for (int k0 = 0; k0 < 256; k0 += 64) {
#pragma unroll
    for (int it = 0; it < 4; ++it) {
      int idx = tid + it * 256;
      int r = idx >> 3;
      int c = (idx & 7) * 8;
      const float* s = A + (size_t)(m0 + r) * 256 + k0 + c;
      float4 v0 = *reinterpret_cast<const float4*>(s);
      float4 v1 = *reinterpret_cast<const float4*>(s + 4);
      u16x8 o = { f2bf(v0.x), f2bf(v0.y), f2bf(v0.z), f2bf(v0.w),
                  f2bf(v1.x), f2bf(v1.y), f2bf(v1.z), f2bf(v1.w) };
      *reinterpret_cast<u16x8*>(&As[r * LDT + c]) = o;
      *reinterpret_cast<u16x8*>(&Ws[r * LDT + c]) =
          *reinterpret_cast<const u16x8*>(W + (size_t)(c0 + r) * 256 + k0 + c);
    }
    __syncthreads();
#pragma unroll
    for (int kk = 0; kk < 2; ++kk) {
      bf16x8 a[4], b[4];
#pragma unroll
      for (int m = 0; m < 4; ++m)
        a[m] = *reinterpret_cast<const bf16x8*>(&As[(wr + m * 16 + lr) * LDT + kk * 32 + lk]);
#pragma unroll
      for (int n = 0; n < 4; ++n)
        b[n] = *reinterpret_cast<const bf16x8*>(&Ws[(wc + n * 16 + lr) * LDT + kk * 32 + lk]);
#pragma unroll
      for (int m = 0; m < 4; ++m)
#pragma unroll
        for (int n = 0; n < 4; ++n)
          acc[m][n] = __builtin_amdgcn_mfma_f32_16x16x32_bf16(a[m], b[n], acc[m][n], 0, 0, 0);
    }
    __syncthreads();
  }

  float rsum[4][4] = {};
#pragma unroll
  for (int n = 0; n < 4; ++n) {
    const int col = c0 + wc + n * 16 + lr;
    const float bv = bias[col];
#pragma unroll
    for (int m = 0; m < 4; ++m) {
#pragma unroll
      for (int j = 0; j < 4; ++j) {
        int row = m0 + wr + m * 16 + (l >> 4) * 4 + j;
        float x = acc[m][n][j] + bv;
        x = (x > 0.0f) ? (x + 1.0f) : __expf(x);
        unsigned short h = f2bf(x);
        Qb[(size_t)row * 256 + col] = h;
        rsum[m][j] += bf2f(h);
      }
    }
  }
#pragma unroll
  for (int mask = 1; mask < 16; mask <<= 1)
#pragma unroll
    for (int m = 0; m < 4; ++m)
#pragma unroll
      for (int j = 0; j < 4; ++j) rsum[m][j] += __shfl_xor(rsum[m][j], mask);
  if (lr == 0) {
#pragma unroll
    for (int m = 0; m < 4; ++m)
#pragma unroll
      for (int j = 0; j < 4; ++j)
        atomicAdd(&qsum[m0 + wr + m * 16 + (l >> 4) * 4 + j], rsum[m][j]);
  }
}

// ---------- projKV: fused K/V projection, transposed outputs Kt/Vt, ksum ----------
__global__ __launch_bounds__(256) void gemm_projkv(const unsigned short* __restrict__ A,
                                                   const unsigned short* __restrict__ Wk,
                                                   const unsigned short* __restrict__ Wv,
                                                   const float* __restrict__ bk,
                                                   const float* __restrict__ bv,
                                                   unsigned short* __restrict__ Kt,
                                                   unsigned short* __restrict__ Vt,
                                                   float* __restrict__ ksum) {
  constexpr int LDT = 72;
  constexpr int LDX = 136; // bounce stride u16: 272B rows (16B-aligned), ~8-way read conflict is epilogue-negligible
  __shared__ unsigned short Smem[3 * 128 * LDT]; // 55.3 KB; bounce (128*136=17408 u16) reuses front
  unsigned short* As  = Smem;
  unsigned short* WsK = Smem + 128 * LDT;
  unsigned short* WsV = Smem + 2 * 128 * LDT;
  unsigned short* Tb  = Smem;

  const int tid = threadIdx.x;
  const int m0 = blockIdx.x * 128;
  const int c0 = blockIdx.y * 128;
  const int b = m0 >> 12;
  const int mloc = m0 & 4095;
  const int w = tid >> 6, l = tid & 63;
  const int wr = (w >> 1) * 64, wc = (w & 1) * 64;
  const int lr = l & 15, lk = (l >> 4) * 8;

  f32x4 acck[4][4] = {}, accv[4][4] = {};

  for (int k0 = 0; k0 < 256; k0 += 64) {
#pragma unroll
    for (int it = 0; it < 4; ++it) {
      int idx = tid + it * 256;
      int r = idx >> 3;
      int c = (idx & 7) * 8;
      *reinterpret_cast<u16x8*>(&As[r * LDT + c]) =
          *reinterpret_cast<const u16x8*>(A + (size_t)(m0 + r) * 256 + k0 + c);
      *reinterpret_cast<u16x8*>(&WsK[r * LDT + c]) =
          *reinterpret_cast<const u16x8*>(Wk + (size_t)(c0 + r) * 256 + k0 + c);
      *reinterpret_cast<u16x8*>(&WsV[r * LDT + c]) =
          *reinterpret_cast<const u16x8*>(Wv + (size_t)(c0 + r) * 256 + k0 + c);
    }
    __syncthreads();
#pragma unroll
    for (int kk = 0; kk < 2; ++kk) {
      bf16x8 a[4], fk[4], fv[4];
#pragma unroll
      for (int m = 0; m < 4; ++m)
        a[m] = *reinterpret_cast<const bf16x8*>(&As[(wr + m * 16 + lr) * LDT + kk * 32 + lk]);
#pragma unroll
      for (int n = 0; n < 4; ++n) {
        fk[n] = *reinterpret_cast<const bf16x8*>(&WsK[(wc + n * 16 + lr) * LDT + kk * 32 + lk]);
        fv[n] = *reinterpret_cast<const bf16x8*>(&WsV[(wc + n * 16 + lr) * LDT + kk * 32 + lk]);
      }
#pragma unroll
      for (int m = 0; m < 4; ++m)
#pragma unroll
        for (int n = 0; n < 4; ++n) {
          acck[m][n] = __builtin_amdgcn_mfma_f32_16x16x32_bf16(a[m], fk[n], acck[m][n], 0, 0, 0);
          accv[m][n] = __builtin_amdgcn_mfma_f32_16x16x32_bf16(a[m], fv[n], accv[m][n], 0, 0, 0);
        }
    }
    __syncthreads();
  }

  // ---- K: activation + rowsum + transpose via LDS bounce ----
  float rsum[4][4] = {};
#pragma unroll
  for (int n = 0; n < 4; ++n) {
    const int col = wc + n * 16 + lr;             // local col 0..127
    const float bb = bk[c0 + col];
#pragma unroll
    for (int m = 0; m < 4; ++m) {
      const int rb = wr + m * 16 + (l >> 4) * 4;
#pragma unroll
      for (int jj = 0; jj < 2; ++jj) {
        float x0 = acck[m][n][2 * jj] + bb;     x0 = (x0 > 0.0f) ? (x0 + 1.0f) : __expf(x0);
        float x1 = acck[m][n][2 * jj + 1] + bb; x1 = (x1 > 0.0f) ? (x1 + 1.0f) : __expf(x1);
        unsigned short h0 = f2bf(x0), h1 = f2bf(x1);
        rsum[m][2 * jj] += bf2f(h0);
        rsum[m][2 * jj + 1] += bf2f(h1);
        *reinterpret_cast<unsigned int*>(&Tb[(size_t)col * LDX + rb + 2 * jj]) =
            (unsigned int)h0 | ((unsigned int)h1 << 16);
      }
    }
  }
#pragma unroll
  for (int mask = 1; mask < 16; mask <<= 1)
#pragma unroll
    for (int m = 0; m < 4; ++m)
#pragma unroll
      for (int j = 0; j < 4; ++j) rsum[m][j] += __shfl_xor(rsum[m][j], mask);
  if (lr == 0) {
#pragma unroll
    for (int m = 0; m < 4; ++m)
#pragma unroll
      for (int j = 0; j < 4; ++j)
        atomicAdd(&ksum[m0 + wr + m * 16 + (l >> 4) * 4 + j], rsum[m][j]);
  }
  __syncthreads();
  {
    const int cl = tid >> 1;
    const int mg = (tid & 1) * 64;
    unsigned short* dst = Kt + ((size_t)b * DDIM + c0 + cl) * NTOK + mloc + mg;
#pragma unroll
    for (int k2 = 0; k2 < 8; ++k2)
      *reinterpret_cast<u16x8*>(dst + k2 * 8) =
          *reinterpret_cast<const u16x8*>(&Tb[(size_t)cl * LDX + mg + k2 * 8]);
  }
  __syncthreads();

  // ---- V: bias only + transpose ----
#pragma unroll
  for (int n = 0; n < 4; ++n) {
    const int col = wc + n * 16 + lr;
    const float bb = bv[c0 + col];
#pragma unroll
    for (int m = 0; m < 4; ++m) {
      const int rb = wr + m * 16 + (l >> 4) * 4;
#pragma unroll
      for (int jj = 0; jj < 2; ++jj) {
        unsigned short h0 = f2bf(accv[m][n][2 * jj] + bb);
        unsigned short h1 = f2bf(accv[m][n][2 * jj + 1] + bb);
        *reinterpret_cast<unsigned int*>(&Tb[(size_t)col * LDX + rb + 2 * jj]) =
            (unsigned int)h0 | ((unsigned int)h1 << 16);
      }
    }
  }
  __syncthreads();
  {
    const int cl = tid >> 1;
    const int mg = (tid & 1) * 64;
    unsigned short* dst = Vt + ((size_t)b * DDIM + c0 + cl) * NTOK + mloc + mg;
#pragma unroll
    for (int k2 = 0; k2 < 8; ++k2)
      *reinterpret_cast<u16x8*>(dst + k2 * 8) =
          *reinterpret_cast<const u16x8*>(&Tb[(size_t)cl * LDX + mg + k2 * 8]);
  }
}

// ---------- KV partials: A=Kt rows(c), B=Vt rows(d), k=m ----------
__global__ __launch_bounds__(256) void kv_gemm(const unsigned short* __restrict__ Kt,
                                               const unsigned short* __restrict__ Vt,
                                               float* __restrict__ partial) {
  constexpr int LDT = 72;
  __shared__ unsigned short As[128 * LDT];
  __shared__ unsigned short Bs[128 * LDT];
  const int tid = threadIdx.x;
  const int b = blockIdx.z;
  const int s = blockIdx.y;
  const int ct0 = (blockIdx.x >> 1) * 128;
  const int dt0 = (blockIdx.x & 1) * 128;
  const int ms = s * 512;

  const int w = tid >> 6, l = tid & 63;
  const int wr = (w >> 1) * 64, wc = (w & 1) * 64;
  const int lr = l & 15, lk = (l >> 4) * 8;

  const size_t kbase = ((size_t)b * DDIM + ct0) * NTOK;
  const size_t vbase = ((size_t)b * DDIM + dt0) * NTOK;

  f32x4 acc[4][4] = {};

  for (int mc = 0; mc < 512; mc += 64) {
#pragma unroll
    for (int it = 0; it < 4; ++it) {
      int idx = tid + it * 256;
      int r = idx >> 3;
      int kg = (idx & 7) * 8;
      *reinterpret_cast<u16x8*>(&As[r * LDT + kg]) =
          *reinterpret_cast<const u16x8*>(Kt + kbase + (size_t)r * NTOK + ms + mc + kg);
      *reinterpret_cast<u16x8*>(&Bs[r * LDT + kg]) =
          *reinterpret_cast<const u16x8*>(Vt + vbase + (size_t)r * NTOK + ms + mc + kg);
    }
    __syncthreads();
#pragma unroll
    for (int kk = 0; kk < 2; ++kk) {
      bf16x8 a[4], bb[4];
#pragma unroll
      for (int m = 0; m < 4; ++m)
        a[m] = *reinterpret_cast<const bf16x8*>(&As[(wr + m * 16 + lr) * LDT + kk * 32 + lk]);
#pragma unroll
      for (int n = 0; n < 4; ++n)
        bb[n] = *reinterpret_cast<const bf16x8*>(&Bs[(wc + n * 16 + lr) * LDT + kk * 32 + lk]);
#pragma unroll
      for (int m = 0; m < 4; ++m)
#pragma unroll
        for (int n = 0; n < 4; ++n)
          acc[m][n] = __builtin_amdgcn_mfma_f32_16x16x32_bf16(a[m], bb[n], acc[m][n], 0, 0, 0);
    }
    __syncthreads();
  }

  float* p = partial + (size_t)(s * BATCH + b) * 65536;
#pragma unroll
  for (int n = 0; n < 4; ++n) {
    int d = dt0 + wc + n * 16 + lr;
#pragma unroll
    for (int m = 0; m < 4; ++m) {
#pragma unroll
      for (int j = 0; j < 4; ++j) {
        int c = ct0 + wr + m * 16 + (l >> 4) * 4 + j;
        p[(size_t)c * 256 + d] = acc[m][n][j];
      }
    }
  }
}

// ---------- KVb[b][c][d] = bf16( sum_s partial ) ----------
__global__ __launch_bounds__(256) void kv_reduce(const float* __restrict__ partial,
                                                 unsigned short* __restrict__ KVb) {
  size_t i = ((size_t)blockIdx.x * 256 + threadIdx.x) * 4;
  float4 acc = *reinterpret_cast<const float4*>(partial + i);
#pragma unroll
  for (int s = 1; s < 8; ++s) {
    float4 v = *reinterpret_cast<const float4*>(partial + (size_t)s * 524288 + i);
    acc.x += v.x; acc.y += v.y; acc.z += v.z; acc.w += v.w;
  }
  u16x4 o = { f2bf(acc.x), f2bf(acc.y), f2bf(acc.z), f2bf(acc.w) };
  *reinterpret_cast<u16x4*>(KVb + i) = o;
}

// ---------- W2T[b][e][c] = sum_d Wo[e,d] * KV[b][c][d] ----------
__global__ __launch_bounds__(256) void w2_gemm(const unsigned short* __restrict__ wob,
                                               const unsigned short* __restrict__ KVb,
                                               unsigned short* __restrict__ W2T) {
  constexpr int LDT = 72;
  __shared__ unsigned short As[128 * LDT];
  __shared__ unsigned short Bs[128 * LDT];
  const int tid = threadIdx.x;
  const int b = blockIdx.z;
  const int e0 = blockIdx.x * 128;
  const int c0 = blockIdx.y * 128;
  const unsigned short* Bsrc = KVb + (size_t)b * 65536;

  const int w = tid >> 6, l = tid & 63;
  const int wr = (w >> 1) * 64, wc = (w & 1) * 64;
  const int lr = l & 15, lk = (l >> 4) * 8;

  f32x4 acc[4][4] = {};

  for (int k0 = 0; k0 < 256; k0 += 64) {
#pragma unroll
    for (int it = 0; it < 4; ++it) {
      int idx = tid + it * 256;
      int r = idx >> 3;
      int c = (idx & 7) * 8;
      *reinterpret_cast<u16x8*>(&As[r * LDT + c]) =
          *reinterpret_cast<const u16x8*>(wob + (size_t)(e0 + r) * 256 + k0 + c);
      *reinterpret_cast<u16x8*>(&Bs[r * LDT + c]) =
          *reinterpret_cast<const u16x8*>(Bsrc + (size_t)(c0 + r) * 256 + k0 + c);
    }
    __syncthreads();
#pragma unroll
    for (int kk = 0; kk < 2; ++kk) {
      bf16x8 a[4], bb[4];
#pragma unroll
      for (int m = 0; m < 4; ++m)
        a[m] = *reinterpret_cast<const bf16x8*>(&As[(wr + m * 16 + lr) * LDT + kk * 32 + lk]);
#pragma unroll
      for (int n = 0; n < 4; ++n)
        bb[n] = *reinterpret_cast<const bf16x8*>(&Bs[(wc + n * 16 + lr) * LDT + kk * 32 + lk]);
#pragma unroll
      for (int m = 0; m < 4; ++m)
#pragma unroll
        for (int n = 0; n < 4; ++n)
          acc[m][n] = __builtin_amdgcn_mfma_f32_16x16x32_bf16(a[m], bb[n], acc[m][n], 0, 0, 0);
    }
    __syncthreads();
  }

  unsigned short* out = W2T + (size_t)b * 65536;
#pragma unroll
  for (int n = 0; n < 4; ++n) {
    int c = c0 + wc + n * 16 + lr;
#pragma unroll
    for (int m = 0; m < 4; ++m) {
#pragma unroll
      for (int j = 0; j < 4; ++j) {
        int e = e0 + wr + m * 16 + (l >> 4) * 4 + j;
        out[(size_t)e * 256 + c] = f2bf(acc[m][n][j]);
      }
    }
  }
}

// ---------- d_out[b,n,e] = (Qb @ W2T^T)/(qsum*ksum+1e-6) + bo ----------
__global__ __launch_bounds__(256) void gemm_final(const unsigned short* __restrict__ Qb,
                                                  const unsigned short* __restrict__ W2T,
                                                  const float* __restrict__ qsum,
                                                  const float* __restrict__ ksum,
                                                  const float* __restrict__ bo,
                                                  float* __restrict__ outp) {
  constexpr int LDT = 72;
  __shared__ unsigned short As[128 * LDT];
  __shared__ unsigned short Bs[128 * LDT];
  const int tid = threadIdx.x;
  const int b = blockIdx.z;
  const int m0 = blockIdx.x * 128;
  const int e0 = blockIdx.y * 128;
  const size_t abase = (size_t)b * NTOK;
  const unsigned short* Bsrc = W2T + (size_t)b * 65536;

  const int w = tid >> 6, l = tid & 63;
  const int wr = (w >> 1) * 64, wc = (w & 1) * 64;
  const int lr = l & 15, lk = (l >> 4) * 8;

  f32x4 acc[4][4] = {};

  for (int k0 = 0; k0 < 256; k0 += 64) {
#pragma unroll
    for (int it = 0; it < 4; ++it) {
      int idx = tid + it * 256;
      int r = idx >> 3, c = (idx & 7) * 8;
      *reinterpret_cast<u16x8*>(&As[r * LDT + c]) =
          *reinterpret_cast<const u16x8*>(Qb + (abase + m0 + r) * 256 + k0 + c);
      *reinterpret_cast<u16x8*>(&Bs[r * LDT + c]) =
          *reinterpret_cast<const u16x8*>(Bsrc + (size_t)(e0 + r) * 256 + k0 + c);
    }
    __syncthreads();
#pragma unroll
    for (int kk = 0; kk < 2; ++kk) {
      bf16x8 a[4], bb[4];
#pragma unroll
      for (int m = 0; m < 4; ++m)
        a[m] = *reinterpret_cast<const bf16x8*>(&As[(wr + m * 16 + lr) * LDT + kk * 32 + lk]);
#pragma unroll
      for (int n = 0; n < 4; ++n)
        bb[n] = *reinterpret_cast<const bf16x8*>(&Bs[(wc + n * 16 + lr) * LDT + kk * 32 + lk]);
#pragma unroll
      for (int m = 0; m < 4; ++m)
#pragma unroll
        for (int n = 0; n < 4; ++n)
          acc[m][n] = __builtin_amdgcn_mfma_f32_16x16x32_bf16(a[m], bb[n], acc[m][n], 0, 0, 0);
    }
    __syncthreads();
  }

#pragma unroll
  for (int n = 0; n < 4; ++n) {
    int col = e0 + wc + n * 16 + lr;
    const float bb = bo[col];
#pragma unroll
    for (int m = 0; m < 4; ++m) {
#pragma unroll
      for (int j = 0; j < 4; ++j) {
        int row = m0 + wr + m * 16 + (l >> 4) * 4 + j;
        size_t g = abase + row;
        float dv = qsum[g] * ksum[g] + 1e-6f;
        outp[g * 256 + col] = acc[m][n][j] / dv + bb;
      }
    }
  }
}

extern "C" void kernel_launch(void* const* d_in, const int* in_sizes, int n_in,
                              void* d_out, int out_size, void* d_ws, size_t ws_size,
                              hipStream_t stream) {
  const float* query     = (const float*)d_in[0];
  const float* key_value = (const float*)d_in[1];
  const float* Wq = (const float*)d_in[2];
  const float* bq = (const float*)d_in[3];
  const float* Wk = (const float*)d_in[4];
  const float* bk = (const float*)d_in[5];
  const float* Wv = (const float*)d_in[6];
  const float* bv = (const float*)d_in[7];
  const float* Wo = (const float*)d_in[8];
  const float* bo = (const float*)d_in[9];

  char* ws = (char*)d_ws;
  const size_t MB = 1ull << 20;
  unsigned short* kv_bf = (unsigned short*)(ws + 0 * MB);   // 16MB
  unsigned short* Qb    = (unsigned short*)(ws + 16 * MB);  // 16MB
  unsigned short* Kt    = (unsigned short*)(ws + 32 * MB);  // 16MB
  unsigned short* Vt    = (unsigned short*)(ws + 48 * MB);  // 16MB
  float* partial        = (float*)(ws + 64 * MB);           // 16MB
  unsigned short* KVb   = (unsigned short*)(ws + 80 * MB);  // 1MB
  unsigned short* W2T   = (unsigned short*)(ws + 81 * MB);  // 1MB
  float* qsum           = (float*)(ws + 82 * MB);           // 128KB
  float* ksum           = (float*)(ws + 82 * MB + 128 * 1024); // 128KB
  unsigned short* wqb   = (unsigned short*)(ws + 82 * MB + 256 * 1024);
  unsigned short* wkb   = (unsigned short*)(ws + 82 * MB + 384 * 1024);
  unsigned short* wvb   = (unsigned short*)(ws + 82 * MB + 512 * 1024);
  unsigned short* wob   = (unsigned short*)(ws + 82 * MB + 640 * 1024);

  hipMemsetAsync(qsum, 0, 2 * 128 * 1024, stream); // qsum+ksum (atomic accumulators)

  conv_w_kernel<<<64, 256, 0, stream>>>(Wq, Wk, Wv, Wo, wqb, wkb, wvb, wob);
  kv_transpose<<<dim3(128, 8, 8), dim3(32, 8), 0, stream>>>(key_value, kv_bf);

  gemm_projq<<<dim3(256, 2), 256, 0, stream>>>(query, wqb, bq, Qb, qsum);
  gemm_projkv<<<dim3(256, 2), 256, 0, stream>>>(kv_bf, wkb, wvb, bk, bv, Kt, Vt, ksum);

  kv_gemm<<<dim3(4, 8, 8), 256, 0, stream>>>(Kt, Vt, partial);
  kv_reduce<<<512, 256, 0, stream>>>(partial, KVb);
  w2_gemm<<<dim3(2, 2, 8), 256, 0, stream>>>(wob, KVb, W2T);

  gemm_final<<<dim3(32, 2, 8), 256, 0, stream>>>(Qb, W2T, qsum, ksum, bo, (float*)d_out);
}

// Round 14
// 221.744 us; speedup vs baseline: 1.1566x; 1.0168x over previous
//
#include <hip/hip_runtime.h>
#include <hip/hip_bf16.h>

// LinearAttention: B=8, N=4096, D=256, HW=N.
//  kv_bf = bf16(key_value^T per batch)                         (kv_transpose)
//  Qb = elu(query@Wq^T+bq)+1 (fp32 A staged once, 512thr), qsum  (projQ)
//  Kt/Vt = projected K/V transposed, ksum                      (projKV)
//  KV[b][c][d] split-K partials + reduce -> bf16               (kv_gemm, kv_reduce)
//  W2T[b][e][c] = sum_d Wo[e,d]*KV[b][c][d]                    (w2_gemm)
//  d_out[n,e] = (Qb @ W2T^T)/(qsum*ksum+1e-6) + bo  (512thr, A staged once)

typedef __attribute__((ext_vector_type(8))) __bf16 bf16x8;
typedef __attribute__((ext_vector_type(4))) float f32x4;
typedef __attribute__((ext_vector_type(4))) unsigned short u16x4;
typedef __attribute__((ext_vector_type(8))) unsigned short u16x8;

#define DEVI __device__ __forceinline__

static constexpr int BATCH = 8;
static constexpr int NTOK  = 4096;
static constexpr int DDIM  = 256;

DEVI float bf2f(unsigned short u) {
  union { float f; unsigned int i; } x; x.i = ((unsigned int)u) << 16; return x.f;
}
DEVI unsigned short f2bf(float f) {
  union { float f; unsigned int i; } x; x.f = f;
  unsigned int r = x.i + 0x7fffu + ((x.i >> 16) & 1u);
  return (unsigned short)(r >> 16);
}

// ---------- weights fp32 -> bf16 ----------
__global__ __launch_bounds__(256) void conv_w_kernel(const float* __restrict__ w0, const float* __restrict__ w1,
                                                     const float* __restrict__ w2, const float* __restrict__ w3,
                                                     unsigned short* __restrict__ o0, unsigned short* __restrict__ o1,
                                                     unsigned short* __restrict__ o2, unsigned short* __restrict__ o3) {
  size_t i = ((size_t)blockIdx.x * 256 + threadIdx.x) * 4;
  float4 a = *reinterpret_cast<const float4*>(w0 + i);
  float4 b = *reinterpret_cast<const float4*>(w1 + i);
  float4 c = *reinterpret_cast<const float4*>(w2 + i);
  float4 d = *reinterpret_cast<const float4*>(w3 + i);
  u16x4 oa = { f2bf(a.x), f2bf(a.y), f2bf(a.z), f2bf(a.w) };
  u16x4 ob = { f2bf(b.x), f2bf(b.y), f2bf(b.z), f2bf(b.w) };
  u16x4 oc = { f2bf(c.x), f2bf(c.y), f2bf(c.z), f2bf(c.w) };
  u16x4 od = { f2bf(d.x), f2bf(d.y), f2bf(d.z), f2bf(d.w) };
  *reinterpret_cast<u16x4*>(o0 + i) = oa;
  *reinterpret_cast<u16x4*>(o1 + i) = ob;
  *reinterpret_cast<u16x4*>(o2 + i) = oc;
  *reinterpret_cast<u16x4*>(o3 + i) = od;
}

// key_value [B][D][M] fp32 -> kv_bf [B][M][D] bf16
__global__ __launch_bounds__(256) void kv_transpose(const float* __restrict__ src,
                                                    unsigned short* __restrict__ dst) {
  __shared__ float t[32][33];
  int b = blockIdx.z;
  int m0 = blockIdx.x * 32, d0 = blockIdx.y * 32;
  int tx = threadIdx.x, ty = threadIdx.y; // 32 x 8
  const float* s = src + ((size_t)b * DDIM + d0) * NTOK + m0;
#pragma unroll
  for (int i = 0; i < 4; ++i) t[ty + i * 8][tx] = s[(size_t)(ty + i * 8) * NTOK + tx];
  __syncthreads();
  unsigned short* d = dst + ((size_t)b * NTOK + m0) * DDIM + d0;
#pragma unroll
  for (int i = 0; i < 4; ++i) d[(size_t)(ty + i * 8) * DDIM + tx] = f2bf(t[tx][ty + i * 8]);
}

// ---------- projQ: 512 thr, full 256-col tile, A(fp32) staged once ----------
__global__ __launch_bounds__(512) void gemm_projq(const float* __restrict__ A,
                                                  const unsigned short* __restrict__ W,
                                                  const float* __restrict__ bias,
                                                  unsigned short* __restrict__ Qb,
                                                  float* __restrict__ qsum) {
  constexpr int LDT = 72;
  __shared__ unsigned short As[128 * LDT];
  __shared__ unsigned short Ws[256 * LDT];

  const int tid = threadIdx.x;
  const int m0 = blockIdx.x * 128;
  const int w = tid >> 6, l = tid & 63;
  const int wr = (w >> 2) * 64, wc = (w & 3) * 64;
  const int lr = l & 15, lk = (l >> 4) * 8;

  f32x4 acc[4][4] = {};

  for (int k0 = 0; k0 < 256; k0 += 64) {
#pragma unroll
    for (int it = 0; it < 2; ++it) {
      int idx = tid + it * 512;     // 0..1023
      int r = idx >> 3;             // 0..127
      int c = (idx & 7) * 8;
      const float* s = A + (size_t)(m0 + r) * 256 + k0 + c;
      float4 v0 = *reinterpret_cast<const float4*>(s);
      float4 v1 = *reinterpret_cast<const float4*>(s + 4);
      u16x8 o = { f2bf(v0.x), f2bf(v0.y), f2bf(v0.z), f2bf(v0.w),
                  f2bf(v1.x), f2bf(v1.y), f2bf(v1.z), f2bf(v1.w) };
      *reinterpret_cast<u16x8*>(&As[r * LDT + c]) = o;
    }
#pragma unroll
    for (int it = 0; it < 4; ++it) {
      int idx = tid + it * 512;     // 0..2047
      int r = idx >> 3;             // 0..255
      int c = (idx & 7) * 8;
      *reinterpret_cast<u16x8*>(&Ws[r * LDT + c]) =
          *reinterpret_cast<const u16x8*>(W + (size_t)r * 256 + k0 + c);
    }
    __syncthreads();
#pragma unroll
    for (int kk = 0; kk < 2; ++kk) {
      bf16x8 a[4], b[4];
#pragma unroll
      for (int m = 0; m < 4; ++m)
        a[m] = *reinterpret_cast<const bf16x8*>(&As[(wr + m * 16 + lr) * LDT + kk * 32 + lk]);
#pragma unroll
      for (int n = 0; n < 4; ++n)
        b[n] = *reinterpret_cast<const bf16x8*>(&Ws[(wc + n * 16 + lr) * LDT + kk * 32 + lk]);
#pragma unroll
      for (int m = 0; m < 4; ++m)
#pragma unroll
        for (int n = 0; n < 4; ++n)
          acc[m][n] = __builtin_amdgcn_mfma_f32_16x16x32_bf16(a[m], b[n], acc[m][n], 0, 0, 0);
    }
    __syncthreads();
  }

  float rsum[4][4] = {};
#pragma unroll
  for (int n = 0; n < 4; ++n) {
    const int col = wc + n * 16 + lr;
    const float bv = bias[col];
#pragma unroll
    for (int m = 0; m < 4; ++m) {
#pragma unroll
      for (int j = 0; j < 4; ++j) {
        int row = m0 + wr + m * 16 + (l >> 4) * 4 + j;
        float x = acc[m][n][j] + bv;
        x = (x > 0.0f) ? (x + 1.0f) : __expf(x);
        unsigned short h = f2bf(x);
        Qb[(size_t)row * 256 + col] = h;
        rsum[m][j] += bf2f(h);
      }
    }
  }
#pragma unroll
  for (int mask = 1; mask < 16; mask <<= 1)
#pragma unroll
    for (int m = 0; m < 4; ++m)
#pragma unroll
      for (int j = 0; j < 4; ++j) rsum[m][j] += __shfl_xor(rsum[m][j], mask);
  if (lr == 0) {
#pragma unroll
    for (int m = 0; m < 4; ++m)
#pragma unroll
      for (int j = 0; j < 4; ++j)
        atomicAdd(&qsum[m0 + wr + m * 16 + (l >> 4) * 4 + j], rsum[m][j]);
  }
}

// ---------- projKV: fused K/V projection, transposed outputs Kt/Vt, ksum ----------
__global__ __launch_bounds__(256) void gemm_projkv(const unsigned short* __restrict__ A,
                                                   const unsigned short* __restrict__ Wk,
                                                   const unsigned short* __restrict__ Wv,
                                                   const float* __restrict__ bk,
                                                   const float* __restrict__ bv,
                                                   unsigned short* __restrict__ Kt,
                                                   unsigned short* __restrict__ Vt,
                                                   float* __restrict__ ksum) {
  constexpr int LDT = 72;
  constexpr int LDX = 136;
  __shared__ unsigned short Smem[3 * 128 * LDT];
  unsigned short* As  = Smem;
  unsigned short* WsK = Smem + 128 * LDT;
  unsigned short* WsV = Smem + 2 * 128 * LDT;
  unsigned short* Tb  = Smem;

  const int tid = threadIdx.x;
  const int m0 = blockIdx.x * 128;
  const int c0 = blockIdx.y * 128;
  const int b = m0 >> 12;
  const int mloc = m0 & 4095;
  const int w = tid >> 6, l = tid & 63;
  const int wr = (w >> 1) * 64, wc = (w & 1) * 64;
  const int lr = l & 15, lk = (l >> 4) * 8;

  f32x4 acck[4][4] = {}, accv[4][4] = {};

  for (int k0 = 0; k0 < 256; k0 += 64) {
#pragma unroll
    for (int it = 0; it < 4; ++it) {
      int idx = tid + it * 256;
      int r = idx >> 3;
      int c = (idx & 7) * 8;
      *reinterpret_cast<u16x8*>(&As[r * LDT + c]) =
          *reinterpret_cast<const u16x8*>(A + (size_t)(m0 + r) * 256 + k0 + c);
      *reinterpret_cast<u16x8*>(&WsK[r * LDT + c]) =
          *reinterpret_cast<const u16x8*>(Wk + (size_t)(c0 + r) * 256 + k0 + c);
      *reinterpret_cast<u16x8*>(&WsV[r * LDT + c]) =
          *reinterpret_cast<const u16x8*>(Wv + (size_t)(c0 + r) * 256 + k0 + c);
    }
    __syncthreads();
#pragma unroll
    for (int kk = 0; kk < 2; ++kk) {
      bf16x8 a[4], fk[4], fv[4];
#pragma unroll
      for (int m = 0; m < 4; ++m)
        a[m] = *reinterpret_cast<const bf16x8*>(&As[(wr + m * 16 + lr) * LDT + kk * 32 + lk]);
#pragma unroll
      for (int n = 0; n < 4; ++n) {
        fk[n] = *reinterpret_cast<const bf16x8*>(&WsK[(wc + n * 16 + lr) * LDT + kk * 32 + lk]);
        fv[n] = *reinterpret_cast<const bf16x8*>(&WsV[(wc + n * 16 + lr) * LDT + kk * 32 + lk]);
      }
#pragma unroll
      for (int m = 0; m < 4; ++m)
#pragma unroll
        for (int n = 0; n < 4; ++n) {
          acck[m][n] = __builtin_amdgcn_mfma_f32_16x16x32_bf16(a[m], fk[n], acck[m][n], 0, 0, 0);
          accv[m][n] = __builtin_amdgcn_mfma_f32_16x16x32_bf16(a[m], fv[n], accv[m][n], 0, 0, 0);
        }
    }
    __syncthreads();
  }

  // ---- K: activation + rowsum + transpose via LDS bounce ----
  float rsum[4][4] = {};
#pragma unroll
  for (int n = 0; n < 4; ++n) {
    const int col = wc + n * 16 + lr;
    const float bb = bk[c0 + col];
#pragma unroll
    for (int m = 0; m < 4; ++m) {
      const int rb = wr + m * 16 + (l >> 4) * 4;
#pragma unroll
      for (int jj = 0; jj < 2; ++jj) {
        float x0 = acck[m][n][2 * jj] + bb;     x0 = (x0 > 0.0f) ? (x0 + 1.0f) : __expf(x0);
        float x1 = acck[m][n][2 * jj + 1] + bb; x1 = (x1 > 0.0f) ? (x1 + 1.0f) : __expf(x1);
        unsigned short h0 = f2bf(x0), h1 = f2bf(x1);
        rsum[m][2 * jj] += bf2f(h0);
        rsum[m][2 * jj + 1] += bf2f(h1);
        *reinterpret_cast<unsigned int*>(&Tb[(size_t)col * LDX + rb + 2 * jj]) =
            (unsigned int)h0 | ((unsigned int)h1 << 16);
      }
    }
  }
#pragma unroll
  for (int mask = 1; mask < 16; mask <<= 1)
#pragma unroll
    for (int m = 0; m < 4; ++m)
#pragma unroll
      for (int j = 0; j < 4; ++j) rsum[m][j] += __shfl_xor(rsum[m][j], mask);
  if (lr == 0) {
#pragma unroll
    for (int m = 0; m < 4; ++m)
#pragma unroll
      for (int j = 0; j < 4; ++j)
        atomicAdd(&ksum[m0 + wr + m * 16 + (l >> 4) * 4 + j], rsum[m][j]);
  }
  __syncthreads();
  {
    const int cl = tid >> 1;
    const int mg = (tid & 1) * 64;
    unsigned short* dst = Kt + ((size_t)b * DDIM + c0 + cl) * NTOK + mloc + mg;
#pragma unroll
    for (int k2 = 0; k2 < 8; ++k2)
      *reinterpret_cast<u16x8*>(dst + k2 * 8) =
          *reinterpret_cast<const u16x8*>(&Tb[(size_t)cl * LDX + mg + k2 * 8]);
  }
  __syncthreads();

  // ---- V: bias only + transpose ----
#pragma unroll
  for (int n = 0; n < 4; ++n) {
    const int col = wc + n * 16 + lr;
    const float bb = bv[c0 + col];
#pragma unroll
    for (int m = 0; m < 4; ++m) {
      const int rb = wr + m * 16 + (l >> 4) * 4;
#pragma unroll
      for (int jj = 0; jj < 2; ++jj) {
        unsigned short h0 = f2bf(accv[m][n][2 * jj] + bb);
        unsigned short h1 = f2bf(accv[m][n][2 * jj + 1] + bb);
        *reinterpret_cast<unsigned int*>(&Tb[(size_t)col * LDX + rb + 2 * jj]) =
            (unsigned int)h0 | ((unsigned int)h1 << 16);
      }
    }
  }
  __syncthreads();
  {
    const int cl = tid >> 1;
    const int mg = (tid & 1) * 64;
    unsigned short* dst = Vt + ((size_t)b * DDIM + c0 + cl) * NTOK + mloc + mg;
#pragma unroll
    for (int k2 = 0; k2 < 8; ++k2)
      *reinterpret_cast<u16x8*>(dst + k2 * 8) =
          *reinterpret_cast<const u16x8*>(&Tb[(size_t)cl * LDX + mg + k2 * 8]);
  }
}

// ---------- KV partials: A=Kt rows(c), B=Vt rows(d), k=m ----------
__global__ __launch_bounds__(256) void kv_gemm(const unsigned short* __restrict__ Kt,
                                               const unsigned short* __restrict__ Vt,
                                               float* __restrict__ partial) {
  constexpr int LDT = 72;
  __shared__ unsigned short As[128 * LDT];
  __shared__ unsigned short Bs[128 * LDT];
  const int tid = threadIdx.x;
  const int b = blockIdx.z;
  const int s = blockIdx.y;
  const int ct0 = (blockIdx.x >> 1) * 128;
  const int dt0 = (blockIdx.x & 1) * 128;
  const int ms = s * 512;

  const int w = tid >> 6, l = tid & 63;
  const int wr = (w >> 1) * 64, wc = (w & 1) * 64;
  const int lr = l & 15, lk = (l >> 4) * 8;

  const size_t kbase = ((size_t)b * DDIM + ct0) * NTOK;
  const size_t vbase = ((size_t)b * DDIM + dt0) * NTOK;

  f32x4 acc[4][4] = {};

  for (int mc = 0; mc < 512; mc += 64) {
#pragma unroll
    for (int it = 0; it < 4; ++it) {
      int idx = tid + it * 256;
      int r = idx >> 3;
      int kg = (idx & 7) * 8;
      *reinterpret_cast<u16x8*>(&As[r * LDT + kg]) =
          *reinterpret_cast<const u16x8*>(Kt + kbase + (size_t)r * NTOK + ms + mc + kg);
      *reinterpret_cast<u16x8*>(&Bs[r * LDT + kg]) =
          *reinterpret_cast<const u16x8*>(Vt + vbase + (size_t)r * NTOK + ms + mc + kg);
    }
    __syncthreads();
#pragma unroll
    for (int kk = 0; kk < 2; ++kk) {
      bf16x8 a[4], bb[4];
#pragma unroll
      for (int m = 0; m < 4; ++m)
        a[m] = *reinterpret_cast<const bf16x8*>(&As[(wr + m * 16 + lr) * LDT + kk * 32 + lk]);
#pragma unroll
      for (int n = 0; n < 4; ++n)
        bb[n] = *reinterpret_cast<const bf16x8*>(&Bs[(wc + n * 16 + lr) * LDT + kk * 32 + lk]);
#pragma unroll
      for (int m = 0; m < 4; ++m)
#pragma unroll
        for (int n = 0; n < 4; ++n)
          acc[m][n] = __builtin_amdgcn_mfma_f32_16x16x32_bf16(a[m], bb[n], acc[m][n], 0, 0, 0);
    }
    __syncthreads();
  }

  float* p = partial + (size_t)(s * BATCH + b) * 65536;
#pragma unroll
  for (int n = 0; n < 4; ++n) {
    int d = dt0 + wc + n * 16 + lr;
#pragma unroll
    for (int m = 0; m < 4; ++m) {
#pragma unroll
      for (int j = 0; j < 4; ++j) {
        int c = ct0 + wr + m * 16 + (l >> 4) * 4 + j;
        p[(size_t)c * 256 + d] = acc[m][n][j];
      }
    }
  }
}

// ---------- KVb[b][c][d] = bf16( sum_s partial ) ----------
__global__ __launch_bounds__(256) void kv_reduce(const float* __restrict__ partial,
                                                 unsigned short* __restrict__ KVb) {
  size_t i = ((size_t)blockIdx.x * 256 + threadIdx.x) * 4;
  float4 acc = *reinterpret_cast<const float4*>(partial + i);
#pragma unroll
  for (int s = 1; s < 8; ++s) {
    float4 v = *reinterpret_cast<const float4*>(partial + (size_t)s * 524288 + i);
    acc.x += v.x; acc.y += v.y; acc.z += v.z; acc.w += v.w;
  }
  u16x4 o = { f2bf(acc.x), f2bf(acc.y), f2bf(acc.z), f2bf(acc.w) };
  *reinterpret_cast<u16x4*>(KVb + i) = o;
}

// ---------- W2T[b][e][c] = sum_d Wo[e,d] * KV[b][c][d] ----------
__global__ __launch_bounds__(256) void w2_gemm(const unsigned short* __restrict__ wob,
                                               const unsigned short* __restrict__ KVb,
                                               unsigned short* __restrict__ W2T) {
  constexpr int LDT = 72;
  __shared__ unsigned short As[128 * LDT];
  __shared__ unsigned short Bs[128 * LDT];
  const int tid = threadIdx.x;
  const int b = blockIdx.z;
  const int e0 = blockIdx.x * 128;
  const int c0 = blockIdx.y * 128;
  const unsigned short* Bsrc = KVb + (size_t)b * 65536;

  const int w = tid >> 6, l = tid & 63;
  const int wr = (w >> 1) * 64, wc = (w & 1) * 64;
  const int lr = l & 15, lk = (l >> 4) * 8;

  f32x4 acc[4][4] = {};

  for (int k0 = 0; k0 < 256; k0 += 64) {
#pragma unroll
    for (int it = 0; it < 4; ++it) {
      int idx = tid + it * 256;
      int r = idx >> 3;
      int c = (idx & 7) * 8;
      *reinterpret_cast<u16x8*>(&As[r * LDT + c]) =
          *reinterpret_cast<const u16x8*>(wob + (size_t)(e0 + r) * 256 + k0 + c);
      *reinterpret_cast<u16x8*>(&Bs[r * LDT + c]) =
          *reinterpret_cast<const u16x8*>(Bsrc + (size_t)(c0 + r) * 256 + k0 + c);
    }
    __syncthreads();
#pragma unroll
    for (int kk = 0; kk < 2; ++kk) {
      bf16x8 a[4], bb[4];
#pragma unroll
      for (int m = 0; m < 4; ++m)
        a[m] = *reinterpret_cast<const bf16x8*>(&As[(wr + m * 16 + lr) * LDT + kk * 32 + lk]);
#pragma unroll
      for (int n = 0; n < 4; ++n)
        bb[n] = *reinterpret_cast<const bf16x8*>(&Bs[(wc + n * 16 + lr) * LDT + kk * 32 + lk]);
#pragma unroll
      for (int m = 0; m < 4; ++m)
#pragma unroll
        for (int n = 0; n < 4; ++n)
          acc[m][n] = __builtin_amdgcn_mfma_f32_16x16x32_bf16(a[m], bb[n], acc[m][n], 0, 0, 0);
    }
    __syncthreads();
  }

  unsigned short* out = W2T + (size_t)b * 65536;
#pragma unroll
  for (int n = 0; n < 4; ++n) {
    int c = c0 + wc + n * 16 + lr;
#pragma unroll
    for (int m = 0; m < 4; ++m) {
#pragma unroll
      for (int j = 0; j < 4; ++j) {
        int e = e0 + wr + m * 16 + (l >> 4) * 4 + j;
        out[(size_t)e * 256 + c] = f2bf(acc[m][n][j]);
      }
    }
  }
}

// ---------- final: 512 thr, full 256-col tile, Qb staged once ----------
__global__ __launch_bounds__(512) void gemm_final(const unsigned short* __restrict__ Qb,
                                                  const unsigned short* __restrict__ W2T,
                                                  const float* __restrict__ qsum,
                                                  const float* __restrict__ ksum,
                                                  const float* __restrict__ bo,
                                                  float* __restrict__ outp) {
  constexpr int LDT = 72;
  __shared__ unsigned short As[128 * LDT];
  __shared__ unsigned short Bs[256 * LDT];
  const int tid = threadIdx.x;
  const int b = blockIdx.z;
  const int m0 = blockIdx.x * 128;
  const size_t abase = (size_t)b * NTOK;
  const unsigned short* Bsrc = W2T + (size_t)b * 65536;

  const int w = tid >> 6, l = tid & 63;
  const int wr = (w >> 2) * 64, wc = (w & 3) * 64;
  const int lr = l & 15, lk = (l >> 4) * 8;

  f32x4 acc[4][4] = {};

  for (int k0 = 0; k0 < 256; k0 += 64) {
#pragma unroll
    for (int it = 0; it < 2; ++it) {
      int idx = tid + it * 512;     // 0..1023
      int r = idx >> 3, c = (idx & 7) * 8;
      *reinterpret_cast<u16x8*>(&As[r * LDT + c]) =
          *reinterpret_cast<const u16x8*>(Qb + (abase + m0 + r) * 256 + k0 + c);
    }
#pragma unroll
    for (int it = 0; it < 4; ++it) {
      int idx = tid + it * 512;     // 0..2047
      int r = idx >> 3, c = (idx & 7) * 8;
      *reinterpret_cast<u16x8*>(&Bs[r * LDT + c]) =
          *reinterpret_cast<const u16x8*>(Bsrc + (size_t)r * 256 + k0 + c);
    }
    __syncthreads();
#pragma unroll
    for (int kk = 0; kk < 2; ++kk) {
      bf16x8 a[4], bb[4];
#pragma unroll
      for (int m = 0; m < 4; ++m)
        a[m] = *reinterpret_cast<const bf16x8*>(&As[(wr + m * 16 + lr) * LDT + kk * 32 + lk]);
#pragma unroll
      for (int n = 0; n < 4; ++n)
        bb[n] = *reinterpret_cast<const bf16x8*>(&Bs[(wc + n * 16 + lr) * LDT + kk * 32 + lk]);
#pragma unroll
      for (int m = 0; m < 4; ++m)
#pragma unroll
        for (int n = 0; n < 4; ++n)
          acc[m][n] = __builtin_amdgcn_mfma_f32_16x16x32_bf16(a[m], bb[n], acc[m][n], 0, 0, 0);
    }
    __syncthreads();
  }

#pragma unroll
  for (int n = 0; n < 4; ++n) {
    int col = wc + n * 16 + lr;
    const float bb = bo[col];
#pragma unroll
    for (int m = 0; m < 4; ++m) {
#pragma unroll
      for (int j = 0; j < 4; ++j) {
        int row = m0 + wr + m * 16 + (l >> 4) * 4 + j;
        size_t g = abase + row;
        float dv = qsum[g] * ksum[g] + 1e-6f;
        outp[g * 256 + col] = acc[m][n][j] / dv + bb;
      }
    }
  }
}

extern "C" void kernel_launch(void* const* d_in, const int* in_sizes, int n_in,
                              void* d_out, int out_size, void* d_ws, size_t ws_size,
                              hipStream_t stream) {
  const float* query     = (const float*)d_in[0];
  const float* key_value = (const float*)d_in[1];
  const float* Wq = (const float*)d_in[2];
  const float* bq = (const float*)d_in[3];
  const float* Wk = (const float*)d_in[4];
  const float* bk = (const float*)d_in[5];
  const float* Wv = (const float*)d_in[6];
  const float* bv = (const float*)d_in[7];
  const float* Wo = (const float*)d_in[8];
  const float* bo = (const float*)d_in[9];

  char* ws = (char*)d_ws;
  const size_t MB = 1ull << 20;
  unsigned short* kv_bf = (unsigned short*)(ws + 0 * MB);   // 16MB
  unsigned short* Qb    = (unsigned short*)(ws + 16 * MB);  // 16MB
  unsigned short* Kt    = (unsigned short*)(ws + 32 * MB);  // 16MB
  unsigned short* Vt    = (unsigned short*)(ws + 48 * MB);  // 16MB
  float* partial        = (float*)(ws + 64 * MB);           // 16MB
  unsigned short* KVb   = (unsigned short*)(ws + 80 * MB);  // 1MB
  unsigned short* W2T   = (unsigned short*)(ws + 81 * MB);  // 1MB
  float* qsum           = (float*)(ws + 82 * MB);           // 128KB
  float* ksum           = (float*)(ws + 82 * MB + 128 * 1024); // 128KB
  unsigned short* wqb   = (unsigned short*)(ws + 82 * MB + 256 * 1024);
  unsigned short* wkb   = (unsigned short*)(ws + 82 * MB + 384 * 1024);
  unsigned short* wvb   = (unsigned short*)(ws + 82 * MB + 512 * 1024);
  unsigned short* wob   = (unsigned short*)(ws + 82 * MB + 640 * 1024);

  hipMemsetAsync(qsum, 0, 2 * 128 * 1024, stream); // qsum+ksum (atomic accumulators)

  conv_w_kernel<<<64, 256, 0, stream>>>(Wq, Wk, Wv, Wo, wqb, wkb, wvb, wob);
  kv_transpose<<<dim3(128, 8, 8), dim3(32, 8), 0, stream>>>(key_value, kv_bf);

  gemm_projq<<<256, 512, 0, stream>>>(query, wqb, bq, Qb, qsum);
  gemm_projkv<<<dim3(256, 2), 256, 0, stream>>>(kv_bf, wkb, wvb, bk, bv, Kt, Vt, ksum);

  kv_gemm<<<dim3(4, 8, 8), 256, 0, stream>>>(Kt, Vt, partial);
  kv_reduce<<<512, 256, 0, stream>>>(partial, KVb);
  w2_gemm<<<dim3(2, 2, 8), 256, 0, stream>>>(wob, KVb, W2T);

  gemm_final<<<dim3(32, 1, 8), 512, 0, stream>>>(Qb, W2T, qsum, ksum, bo, (float*)d_out);
}